// Round 6
// baseline (333.116 us; speedup 1.0000x reference)
//
#include <hip/hip_runtime.h>
#include <hip/hip_bf16.h>
#include <stdint.h>

#define EPSF 1e-8f

typedef __attribute__((ext_vector_type(8))) short short8;
typedef __attribute__((ext_vector_type(8))) _Float16 half8;
typedef __attribute__((ext_vector_type(4))) float floatx4;

__device__ __forceinline__ unsigned short f2h(float f) {
    _Float16 h = (_Float16)f;
    return __builtin_bit_cast(unsigned short, h);
}
__device__ __forceinline__ float h2f(unsigned short u) {
    return (float)__builtin_bit_cast(_Float16, u);
}

// ---------------- fused conversion kernel (float4-vectorized) ----------------

__global__ void prep_kernel(const float4* __restrict__ x4, ushort4* __restrict__ x16,
                            const float4* __restrict__ wi4, ushort4* __restrict__ wi16,
                            const float4* __restrict__ wo4, ushort4* __restrict__ wo16,
                            int nx4, int nw4, int nwo4) {
    int i = blockIdx.x * blockDim.x + threadIdx.x;
    float4 f; ushort4 u;
    if (i < nx4) {
        f = x4[i];
        u.x = f2h(f.x); u.y = f2h(f.y); u.z = f2h(f.z); u.w = f2h(f.w);
        x16[i] = u;
    } else if (i < nx4 + nw4) {
        int j = i - nx4;
        f = wi4[j];
        u.x = f2h(f.x); u.y = f2h(f.y); u.z = f2h(f.z); u.w = f2h(f.w);
        wi16[j] = u;
    } else if (i < nx4 + nw4 + nwo4) {
        int j = i - nx4 - nw4;
        f = wo4[j];
        u.x = f2h(f.x); u.y = f2h(f.y); u.z = f2h(f.z); u.w = f2h(f.w);
        wo16[j] = u;
    }
}

__device__ __forceinline__ void gld16(const unsigned short* g, unsigned short* l) {
    __builtin_amdgcn_global_load_lds(
        (const __attribute__((address_space(1))) unsigned int*)g,
        (__attribute__((address_space(3))) unsigned int*)l, 16, 0, 0);
}

// ---------------- GEMM1: r2/r5 structure (unchanged, proven ~910TF) ----------------

template <bool HALFOUT>
__global__ __launch_bounds__(512, 2)
void gemm8p(const unsigned short* __restrict__ Am, const unsigned short* __restrict__ Bm,
            const float* __restrict__ bias, void* __restrict__ Cv,
            int M, int N, int K) {
    constexpr int BM = 256, BN = 128, BK = 64;
    constexpr int ASZ  = BM * BK;
    constexpr int BSZ  = BN * BK;
    constexpr int SLOT = ASZ + BSZ;
    extern __shared__ unsigned short smem[];

    const int tid  = threadIdx.x;
    const int lane = tid & 63;
    const int wid  = tid >> 6;
    const int wr   = wid >> 1, wc = wid & 1;
    const int q4   = lane >> 4;
    const int m16  = lane & 15;
    const int x7   = m16 & 7;

    const int nbx = N / BN;
    const int nwg = gridDim.x;
    const int q   = nwg >> 3;
    const int wg  = blockIdx.x;
    const int sz  = (wg & 7) * q + (wg >> 3);
    const int bx  = sz % nbx, by = sz / nbx;
    const int rowA0 = by * BM, rowB0 = bx * BN;

    const int rA = tid >> 3, cA = tid & 7;
    const int cg = cA ^ (rA & 7);
    const unsigned short* srcA = Am + (size_t)(rowA0 + rA) * K + cg * 8;
    const unsigned short* srcB = Bm + (size_t)(rowB0 + rA) * K + cg * 8;
    const int dA = tid * 8;

    int aoffm[4], boffn[4];
#pragma unroll
    for (int m = 0; m < 4; ++m) aoffm[m] = (wr * 64 + m * 16 + m16) * BK;
#pragma unroll
    for (int n = 0; n < 4; ++n) boffn[n] = (wc * 64 + n * 16 + m16) * BK;

    floatx4 acc[4][4];
#pragma unroll
    for (int m = 0; m < 4; ++m)
#pragma unroll
        for (int n = 0; n < 4; ++n)
#pragma unroll
            for (int r = 0; r < 4; ++r) acc[m][n][r] = 0.f;

    const int NT = K / BK;

    auto stageA = [&](int s, int t, int j) {
        gld16(srcA + (size_t)(j * 64) * K + (size_t)t * BK,
              smem + s * SLOT + j * 4096 + dA);
    };
    auto stageB = [&](int s, int t, int j) {
        gld16(srcB + (size_t)(j * 64) * K + (size_t)t * BK,
              smem + s * SLOT + ASZ + j * 4096 + dA);
    };
    auto RD = [&](const unsigned short* tA, const unsigned short* tB, int kh,
                  short8* Ra, short8* Rb) {
        const int xo = ((kh * 4 + q4) ^ x7) * 8;
#pragma unroll
        for (int m = 0; m < 4; ++m) Ra[m] = *(const short8*)(tA + aoffm[m] + xo);
#pragma unroll
        for (int n = 0; n < 4; ++n) Rb[n] = *(const short8*)(tB + boffn[n] + xo);
    };
    auto MM = [&](short8* Ra, short8* Rb) {
        __builtin_amdgcn_s_setprio(1);
#pragma unroll
        for (int m = 0; m < 4; ++m)
#pragma unroll
            for (int n = 0; n < 4; ++n)
                acc[m][n] = __builtin_amdgcn_mfma_f32_16x16x32_f16(
                    __builtin_bit_cast(half8, Ra[m]), __builtin_bit_cast(half8, Rb[n]),
                    acc[m][n], 0, 0, 0);
        __builtin_amdgcn_s_setprio(0);
    };

#pragma unroll
    for (int j = 0; j < 4; ++j) stageA(0, 0, j);
    stageB(0, 0, 0); stageB(0, 0, 1);
#pragma unroll
    for (int j = 0; j < 4; ++j) stageA(1, 1, j);
    stageB(1, 1, 0); stageB(1, 1, 1);

    asm volatile("s_waitcnt vmcnt(6)" ::: "memory");
    __builtin_amdgcn_s_barrier();
    __builtin_amdgcn_sched_barrier(0);

    short8 RA0[4], RB0[4], RA1[4], RB1[4];
    RD(smem, smem + ASZ, 0, RA0, RB0);

    int s0 = 0;
    for (int t = 0; t < NT; ++t) {
        __builtin_amdgcn_s_barrier();
        __builtin_amdgcn_sched_barrier(0);

        int s1 = s0 + 1; if (s1 == 3) s1 = 0;
        int s2 = s1 + 1; if (s2 == 3) s2 = 0;
        const unsigned short* tA  = smem + s0 * SLOT;
        const unsigned short* tB  = tA + ASZ;
        const unsigned short* tA1 = smem + s1 * SLOT;
        const unsigned short* tB1 = tA1 + ASZ;

        if (t + 2 < NT) {
#pragma unroll
            for (int j = 0; j < 4; ++j) stageA(s2, t + 2, j);
            stageB(s2, t + 2, 0); stageB(s2, t + 2, 1);
        }

        RD(tA, tB, 1, RA1, RB1);
        MM(RA0, RB0);

        if (t + 2 < NT) asm volatile("s_waitcnt vmcnt(6)" ::: "memory");
        else            asm volatile("s_waitcnt vmcnt(0)" ::: "memory");
        __builtin_amdgcn_s_barrier();
        __builtin_amdgcn_sched_barrier(0);

        if (t + 1 < NT) RD(tA1, tB1, 0, RA0, RB0);
        MM(RA1, RB1);

        s0 = s1;
    }

#pragma unroll
    for (int m = 0; m < 4; ++m) {
#pragma unroll
        for (int n = 0; n < 4; ++n) {
            int col  = rowB0 + wc * 64 + n * 16 + m16;
            float bvl = bias[col];
#pragma unroll
            for (int r = 0; r < 4; ++r) {
                int row = rowA0 + wr * 64 + m * 16 + q4 * 4 + r;
                if (HALFOUT)
                    ((unsigned short*)Cv)[(size_t)row * N + col] = f2h(acc[m][n][r] + bvl);
                else
                    ((float*)Cv)[(size_t)row * N + col] = acc[m][n][r] + bvl;
            }
        }
    }
}

// ---------------- GEMM2: 256x256 8-phase template port + K-split 2 ----------------
// m201 geometry (the regime-gate quadrant that works): BM=BN=256, BK=64,
// 8 waves as 2M x 4N, PER-WAVE 128x64 (375 B/MFMA vs 512 at 64x64 waves).
// 2-slot LDS dbuf (2 x 64KB = 128KB). Per K-tile: 4 phases, each
// {ds_read quadrant, stage 2-3 gload_lds of tile t+1, barrier, lgkmcnt(0)+
//  sched_barrier, setprio(1), 16 MFMA, setprio(0), barrier}.
// Quadrant order (mh,nh) = (0,0),(0,1),(1,1),(1,0): A re-read once per mh
// (8 reads), B per nh kept in regs (reused at phase 3); reads/phase =
// 12/4/8/0. Staging front-loaded (2/3/3/0) so entry vmcnt(0) drains only
// >=1.5-phase-old loads (2-slot depth makes counted-vmcnt degenerate).
// K-split: grid 32(by) x 4(bx) x 2(ks); each block does K/2; results
// combined via fp32 atomicAdd onto memset-zeroed C; bias added by ks==0.
// Slot-reuse safety: staging of t+2 (into slot t%2) first issues after the
// t+1 entry barrier; every wave's last reads of slot t%2 complete at its
// own lgkmcnt(0) before phase-3 MFMA of tile t, which precedes that
// barrier -> race-free.
// Fragment layouts (16x16x32, verified): A/B row|col=lane&15, k=(lane>>4)*8+i;
// C/D col=lane&15, row=(lane>>4)*4+reg.
// Swizzle: same 0-conflict XOR-chunk scheme as gemm8p (pre-swizzled global
// source, linear LDS dest, XOR on read).

__global__ __launch_bounds__(512, 2)
void gemm256(const unsigned short* __restrict__ Am, const unsigned short* __restrict__ Bm,
             const float* __restrict__ bias, float* __restrict__ C,
             int M, int N, int K, int KS) {
    constexpr int BM = 256, BN = 256, BK = 64;
    constexpr int ASZ  = BM * BK;         // 16384 ushorts (32 KB)
    constexpr int SLOT = (BM + BN) * BK;  // 32768 ushorts (64 KB)
    extern __shared__ unsigned short smem[];   // 2 slots = 128 KB

    const int tid  = threadIdx.x;
    const int lane = tid & 63;
    const int wid  = tid >> 6;           // 0..7
    const int wr   = wid >> 2;           // 0..1 : 128-row strip
    const int wc   = wid & 3;            // 0..3 : 64-col strip
    const int q4   = lane >> 4;
    const int m16  = lane & 15;

    // XCD swizzle over linear grid of 256, then decompose (32 by, 4 bx, 2 ks)
    const int nwg = gridDim.x;
    const int qq  = nwg >> 3;
    const int wg  = blockIdx.x;
    const int sz  = (wg & 7) * qq + (wg >> 3);
    const int ks  = sz >> 7;             // 0..1
    const int rm  = sz & 127;
    const int by  = rm >> 2, bx = rm & 3;
    const int rowA0 = by * BM, rowB0 = bx * BN;
    const int k0 = ks * KS;

    // staging: thread covers one 16B chunk; pre-swizzled source, linear dest
    const int rS = tid >> 3, cS = tid & 7;
    const int cg = cS ^ (rS & 7);
    const unsigned short* srcA = Am + (size_t)(rowA0 + rS) * K + k0 + cg * 8;
    const unsigned short* srcB = Bm + (size_t)(rowB0 + rS) * K + k0 + cg * 8;
    const int dA = tid * 8;

    auto stA = [&](int s, int t, int j) {   // j = 64-row group 0..3
        gld16(srcA + (size_t)(j * 64) * K + (size_t)t * BK,
              smem + s * SLOT + j * 4096 + dA);
    };
    auto stB = [&](int s, int t, int j) {
        gld16(srcB + (size_t)(j * 64) * K + (size_t)t * BK,
              smem + s * SLOT + ASZ + j * 4096 + dA);
    };

    // fragment row indices
    int arow[8], brow[4];
#pragma unroll
    for (int i = 0; i < 8; ++i) arow[i] = wr * 128 + i * 16 + m16;
#pragma unroll
    for (int i = 0; i < 4; ++i) brow[i] = wc * 64 + i * 16 + m16;

    floatx4 acc[8][4];
#pragma unroll
    for (int m = 0; m < 8; ++m)
#pragma unroll
        for (int n = 0; n < 4; ++n)
#pragma unroll
            for (int r = 0; r < 4; ++r) acc[m][n][r] = 0.f;

    short8 Af[4][2];        // current mh: 4 mf x 2 ksteps (32 VGPR)
    short8 Bf[2][2][2];     // [nh][nf][kstep] both halves live (32 VGPR)

    auto RDA = [&](const unsigned short* base, int mh) {
#pragma unroll
        for (int i = 0; i < 4; ++i) {
            int rr = arow[mh * 4 + i];
#pragma unroll
            for (int k = 0; k < 2; ++k)
                Af[i][k] = *(const short8*)(base + rr * 64 + (((k * 4 + q4) ^ (rr & 7)) * 8));
        }
    };
    auto RDB = [&](const unsigned short* base, int nh) {
#pragma unroll
        for (int i = 0; i < 2; ++i) {
            int rr = brow[nh * 2 + i];
#pragma unroll
            for (int k = 0; k < 2; ++k)
                Bf[nh][i][k] = *(const short8*)(base + ASZ + rr * 64 + (((k * 4 + q4) ^ (rr & 7)) * 8));
        }
    };
    auto MMp = [&](int mh, int nh) {
        __builtin_amdgcn_s_setprio(1);
#pragma unroll
        for (int i = 0; i < 4; ++i)
#pragma unroll
            for (int j = 0; j < 2; ++j)
#pragma unroll
                for (int k = 0; k < 2; ++k)
                    acc[mh * 4 + i][nh * 2 + j] = __builtin_amdgcn_mfma_f32_16x16x32_f16(
                        __builtin_bit_cast(half8, Af[i][k]),
                        __builtin_bit_cast(half8, Bf[nh][j][k]),
                        acc[mh * 4 + i][nh * 2 + j], 0, 0, 0);
        __builtin_amdgcn_s_setprio(0);
    };

    const int NT = KS / BK;   // 32

    // prologue: stage tile 0 fully into slot 0 (8 sweeps)
#pragma unroll
    for (int j = 0; j < 4; ++j) stA(0, 0, j);
#pragma unroll
    for (int j = 0; j < 4; ++j) stB(0, 0, j);

    int s0 = 0;
    for (int t = 0; t < NT; ++t) {
        // tile entry: own staging contributions drained + block-wide sync.
        // Outstanding loads here are >=1.5 phases old (front-loaded staging).
        asm volatile("s_waitcnt vmcnt(0)" ::: "memory");
        __builtin_amdgcn_s_barrier();
        __builtin_amdgcn_sched_barrier(0);

        const unsigned short* base = smem + s0 * SLOT;
        const int s1 = s0 ^ 1;
        const bool pf = (t + 1 < NT);

        // phase 0: quadrant (0,0) — 12 reads, 2 stage sweeps
        RDA(base, 0); RDB(base, 0);
        if (pf) { stA(s1, t + 1, 0); stA(s1, t + 1, 1); }
        __builtin_amdgcn_s_barrier();
        asm volatile("s_waitcnt lgkmcnt(0)" ::: "memory");
        __builtin_amdgcn_sched_barrier(0);
        MMp(0, 0);
        __builtin_amdgcn_s_barrier();

        // phase 1: quadrant (0,1) — 4 reads, 3 stage sweeps
        RDB(base, 1);
        if (pf) { stA(s1, t + 1, 2); stA(s1, t + 1, 3); stB(s1, t + 1, 0); }
        __builtin_amdgcn_s_barrier();
        asm volatile("s_waitcnt lgkmcnt(0)" ::: "memory");
        __builtin_amdgcn_sched_barrier(0);
        MMp(0, 1);
        __builtin_amdgcn_s_barrier();

        // phase 2: quadrant (1,1) — 8 reads, 3 stage sweeps
        RDA(base, 1);
        if (pf) { stB(s1, t + 1, 1); stB(s1, t + 1, 2); stB(s1, t + 1, 3); }
        __builtin_amdgcn_s_barrier();
        asm volatile("s_waitcnt lgkmcnt(0)" ::: "memory");
        __builtin_amdgcn_sched_barrier(0);
        MMp(1, 1);
        __builtin_amdgcn_s_barrier();

        // phase 3: quadrant (1,0) — 0 reads (Bf[0] still live), 0 stage
        MMp(1, 0);

        s0 = s1;
    }

    // epilogue: atomicAdd partials; bias added once (ks==0 blocks)
#pragma unroll
    for (int m = 0; m < 8; ++m) {
#pragma unroll
        for (int n = 0; n < 4; ++n) {
            int col = rowB0 + wc * 64 + n * 16 + m16;
            float bvl = (ks == 0) ? bias[col] : 0.f;
#pragma unroll
            for (int r = 0; r < 4; ++r) {
                int row = rowA0 + wr * 128 + m * 16 + q4 * 4 + r;
                atomicAdd(&C[(size_t)row * N + col], acc[m][n][r] + bvl);
            }
        }
    }
}

// ---------------- hierarchical quaternion prefix-product scan ----------------

struct Q { float w, x, y, z; };

__device__ __forceinline__ Q qmul(Q a, Q b) {
    Q r;
    r.w = a.w * b.w - a.x * b.x - a.y * b.y - a.z * b.z;
    r.x = a.w * b.x + a.x * b.w + a.y * b.z - a.z * b.y;
    r.y = a.w * b.y - a.x * b.z + a.y * b.w + a.z * b.x;
    r.z = a.w * b.z + a.x * b.y - a.y * b.x + a.z * b.w;
    return r;
}
__device__ __forceinline__ Q qnorm(Q a) {
    float nn = a.w * a.w + a.x * a.x + a.y * a.y + a.z * a.z;
    float inv = __frsqrt_rn(nn);
    Q r; r.w = a.w * inv; r.x = a.x * inv; r.y = a.y * inv; r.z = a.z * inv;
    return r;
}
__device__ __forceinline__ Q vquat(float vx, float vy, float vz) {
    float th = sqrtf(vx * vx + vy * vy + vz * vz);
    float s_, c_;
    __sincosf(th, &s_, &c_);
    float k = __fdividef(s_, th + EPSF);
    Q q; q.w = c_; q.x = k * vx; q.y = k * vy; q.z = k * vz;
    return q;
}

#define SEG  64
#define NSEG 32

__global__ __launch_bounds__(256)
void seg_prod_kernel(const unsigned short* __restrict__ v, float* __restrict__ partials,
                     int S, int H) {
    const int b  = blockIdx.z;
    const int h  = blockIdx.y * 64 + (threadIdx.x & 63);
    const int sg = blockIdx.x * 4 + (threadIdx.x >> 6);
    const int s0 = sg * SEG;
    const size_t vstep = (size_t)3 * H;
    const unsigned short* vp = v + ((size_t)b * S + s0) * vstep + (size_t)h * 3;

    constexpr int CH = 8;
    float ax[CH], ay[CH], az[CH], bx[CH], by[CH], bz[CH];
#pragma unroll
    for (int i = 0; i < CH; ++i) {
        ax[i] = h2f(vp[i * vstep + 0]); ay[i] = h2f(vp[i * vstep + 1]); az[i] = h2f(vp[i * vstep + 2]);
    }
    Q c = {1.f, 0.f, 0.f, 0.f};
    const int NC = SEG / CH;
    for (int cc = 0; cc < NC; cc += 2) {
        if (cc + 1 < NC) {
            const unsigned short* p = vp + (size_t)(cc + 1) * CH * vstep;
#pragma unroll
            for (int i = 0; i < CH; ++i) {
                bx[i] = h2f(p[i * vstep + 0]); by[i] = h2f(p[i * vstep + 1]); bz[i] = h2f(p[i * vstep + 2]);
            }
        }
#pragma unroll
        for (int i = 0; i < CH; ++i) c = qmul(vquat(ax[i], ay[i], az[i]), c);
        if (cc + 2 < NC) {
            const unsigned short* p = vp + (size_t)(cc + 2) * CH * vstep;
#pragma unroll
            for (int i = 0; i < CH; ++i) {
                ax[i] = h2f(p[i * vstep + 0]); ay[i] = h2f(p[i * vstep + 1]); az[i] = h2f(p[i * vstep + 2]);
            }
        }
#pragma unroll
        for (int i = 0; i < CH; ++i) c = qmul(vquat(bx[i], by[i], bz[i]), c);
    }
    float4* dst = (float4*)(partials + (((size_t)b * NSEG + sg) * H + h) * 4);
    *dst = make_float4(c.w, c.x, c.y, c.z);
}

__global__ __launch_bounds__(256)
void apply_kernel(const unsigned short* __restrict__ v, const float* __restrict__ partials,
                  unsigned short* __restrict__ st, float* __restrict__ m_final,
                  int S, int H) {
    const int b   = blockIdx.z;
    const int hb  = blockIdx.y * 64;
    const int hl  = threadIdx.x & 63;
    const int h   = hb + hl;
    const int sg  = blockIdx.x * 4 + (threadIdx.x >> 6);
    const int s0  = sg * SEG;
    const size_t vstep = (size_t)3 * H;
    const size_t sstep = (size_t)4 * H;
    const unsigned short* vp = v + ((size_t)b * S + s0) * vstep + (size_t)h * 3;
    unsigned short* sp = st + ((size_t)b * S + s0) * sstep + (size_t)h * 4;

    __shared__ float4 lp[NSEG][64];
    for (int i = threadIdx.x; i < NSEG * 64; i += 256) {
        int s2 = i >> 6, hh = i & 63;
        lp[s2][hh] = *(const float4*)(partials + (((size_t)b * NSEG + s2) * H + hb + hh) * 4);
    }
    __syncthreads();

    Q R = {1.f, 0.f, 0.f, 0.f};
    for (int s2 = 0; s2 < sg; ++s2) {
        float4 pv = lp[s2][hl];
        Q pq = {pv.x, pv.y, pv.z, pv.w};
        R = qmul(pq, R);
    }

    constexpr int CH = 8;
    float ax[CH], ay[CH], az[CH], bx[CH], by[CH], bz[CH];
#pragma unroll
    for (int i = 0; i < CH; ++i) {
        ax[i] = h2f(vp[i * vstep + 0]); ay[i] = h2f(vp[i * vstep + 1]); az[i] = h2f(vp[i * vstep + 2]);
    }
    const int NC = SEG / CH;
    for (int cc = 0; cc < NC; cc += 2) {
        if (cc + 1 < NC) {
            const unsigned short* pp = vp + (size_t)(cc + 1) * CH * vstep;
#pragma unroll
            for (int i = 0; i < CH; ++i) {
                bx[i] = h2f(pp[i * vstep + 0]); by[i] = h2f(pp[i * vstep + 1]); bz[i] = h2f(pp[i * vstep + 2]);
            }
        }
#pragma unroll
        for (int i = 0; i < CH; ++i) {
            R = qmul(vquat(ax[i], ay[i], az[i]), R);
            Q m = qnorm(R);
            ushort4 u; u.x = f2h(m.w); u.y = f2h(m.x); u.z = f2h(m.y); u.w = f2h(m.z);
            *(ushort4*)(sp + (size_t)(cc * CH + i) * sstep) = u;
        }
        if (cc + 2 < NC) {
            const unsigned short* pp = vp + (size_t)(cc + 2) * CH * vstep;
#pragma unroll
            for (int i = 0; i < CH; ++i) {
                ax[i] = h2f(pp[i * vstep + 0]); ay[i] = h2f(pp[i * vstep + 1]); az[i] = h2f(pp[i * vstep + 2]);
            }
        }
#pragma unroll
        for (int i = 0; i < CH; ++i) {
            R = qmul(vquat(bx[i], by[i], bz[i]), R);
            Q m = qnorm(R);
            ushort4 u; u.x = f2h(m.w); u.y = f2h(m.x); u.z = f2h(m.y); u.w = f2h(m.z);
            *(ushort4*)(sp + (size_t)((cc + 1) * CH + i) * sstep) = u;
        }
    }

    if (sg == NSEG - 1) {
        Q m = qnorm(R);
        float* mf = m_final + ((size_t)b * H + h) * 4;
        mf[0] = m.w; mf[1] = m.x; mf[2] = m.y; mf[3] = m.z;
    }
}

// ---------------- launch ----------------

extern "C" void kernel_launch(void* const* d_in, const int* in_sizes, int n_in,
                              void* d_out, int out_size, void* d_ws, size_t ws_size,
                              hipStream_t stream) {
    const float* x     = (const float*)d_in[0];
    const float* W_in  = (const float*)d_in[1];
    const float* b_in  = (const float*)d_in[2];
    const float* W_out = (const float*)d_in[3];
    const float* b_out = (const float*)d_in[4];
    float* out = (float*)d_out;

    const int B = 4, S = 2048, D = 1024, H = 1024;
    const int M  = B * S;    // 8192
    const int N1 = 3 * H;    // 3072
    const int K1 = D;        // 1024
    const int N2 = D;        // 1024
    const int K2 = 4 * H;    // 4096

    char* ws = (char*)d_ws;
    unsigned short* v    = (unsigned short*)(ws);
    unsigned short* st   = (unsigned short*)(ws + 50331648u);
    unsigned short* x16  = (unsigned short*)(ws + 50331648u);
    unsigned short* wi16 = (unsigned short*)(ws + 50331648u + 16777216u);
    unsigned short* wo16 = (unsigned short*)(ws + 117440512u);

    // partials (2 MB) live in d_out — consumed by apply BEFORE the memset+GEMM2.
    float* partials = out;

    const int nx  = M * K1;
    const int nw  = N1 * K1;
    const int nwo = N2 * K2;
    const int n4  = (nx + nw + nwo) / 4;

    constexpr int LDSB1 = 147456;   // gemm8p: 3 x 48 KB
    constexpr int LDSB2 = 131072;   // gemm256: 2 x 64 KB
    static int attr_done = 0;
    if (!attr_done) {
        hipFuncSetAttribute(reinterpret_cast<const void*>(&gemm8p<true>),
                            hipFuncAttributeMaxDynamicSharedMemorySize, LDSB1);
        hipFuncSetAttribute(reinterpret_cast<const void*>(&gemm256),
                            hipFuncAttributeMaxDynamicSharedMemorySize, LDSB2);
        attr_done = 1;
    }

    prep_kernel<<<(n4 + 255) / 256, 256, 0, stream>>>(
        (const float4*)x, (ushort4*)x16, (const float4*)W_in, (ushort4*)wi16,
        (const float4*)W_out, (ushort4*)wo16, nx / 4, nw / 4, nwo / 4);

    // v = x @ W_in^T + b_in   (fp16 out; proven r2-structure)
    gemm8p<true><<<dim3((M / 256) * (N1 / 128)), 512, LDSB1, stream>>>(
        x16, wi16, b_in, v, M, N1, K1);

    // hierarchical scan
    dim3 sg_grid(NSEG / 4, H / 64, B);
    seg_prod_kernel<<<sg_grid, 256, 0, stream>>>(v, partials, S, H);
    apply_kernel<<<sg_grid, 256, 0, stream>>>(v, partials, st, out + (size_t)M * D, S, H);

    // out = states @ W_out^T + b_out  (256^2 8-phase template, K-split 2,
    // fp32 atomicAdd onto zeroed out; memset after apply consumed partials)
    hipMemsetAsync(out, 0, (size_t)M * D * sizeof(float), stream);
    gemm256<<<dim3(32 * 4 * 2), 512, LDSB2, stream>>>(
        st, wo16, b_out, out, M, N2, K2, K2 / 2);
}

// Round 7
// 308.470 us; speedup vs baseline: 1.0799x; 1.0799x over previous
//
#include <hip/hip_runtime.h>
#include <hip/hip_bf16.h>
#include <stdint.h>

#define EPSF 1e-8f

typedef __attribute__((ext_vector_type(8))) short short8;
typedef __attribute__((ext_vector_type(8))) _Float16 half8;
typedef __attribute__((ext_vector_type(4))) float floatx4;

__device__ __forceinline__ unsigned short f2h(float f) {
    _Float16 h = (_Float16)f;
    return __builtin_bit_cast(unsigned short, h);
}
__device__ __forceinline__ float h2f(unsigned short u) {
    return (float)__builtin_bit_cast(_Float16, u);
}

// ---------------- fused conversion kernel (float4-vectorized) ----------------

__global__ void prep_kernel(const float4* __restrict__ x4, ushort4* __restrict__ x16,
                            const float4* __restrict__ wi4, ushort4* __restrict__ wi16,
                            const float4* __restrict__ wo4, ushort4* __restrict__ wo16,
                            int nx4, int nw4, int nwo4) {
    int i = blockIdx.x * blockDim.x + threadIdx.x;
    float4 f; ushort4 u;
    if (i < nx4) {
        f = x4[i];
        u.x = f2h(f.x); u.y = f2h(f.y); u.z = f2h(f.z); u.w = f2h(f.w);
        x16[i] = u;
    } else if (i < nx4 + nw4) {
        int j = i - nx4;
        f = wi4[j];
        u.x = f2h(f.x); u.y = f2h(f.y); u.z = f2h(f.z); u.w = f2h(f.w);
        wi16[j] = u;
    } else if (i < nx4 + nw4 + nwo4) {
        int j = i - nx4 - nw4;
        f = wo4[j];
        u.x = f2h(f.x); u.y = f2h(f.y); u.z = f2h(f.z); u.w = f2h(f.w);
        wo16[j] = u;
    }
}

// ---------------- pipelined MFMA GEMM (C = A * B^T + bias), fp16 ----------------
// r5 structure, proven (910 TF-class, 2835 cyc/tile, 0 bank conflicts).
// r6 post-mortem: 256^2 4-phase port with entry vmcnt(0) = drain-0
// anti-pattern (m218), 108us vs this kernel's 76us -> reverted, parked.
//   BM=256 x BN=128 x BK=64, 8 waves (4M x 2N), per-wave 64x64 via 16x16x32,
//   4x4 frags. Per tile: read half1 while MFMA half0; cross-tile read-ahead
//   (t+1, half0) during half1's MFMA, legalized by mid-tile {vmcnt(6);
//   barrier}. 3 LDS slots (48 KB each), distance-2 gload_lds prefetch.
//   2 barriers/tile, both non-draining (counted vmcnt only).
// Fragment layouts (16x16x32): A/B row|col=lane&15, k=(lane>>4)*8+i;
//   C/D col=lane&15, row=(lane>>4)*4+reg.
// LDS swizzle: chunk col c holds global chunk c ^ (row&7); read chunk
//   (kh*4 + q4) ^ (row&7) — measured 0 conflicts.

__device__ __forceinline__ void gld16(const unsigned short* g, unsigned short* l) {
    __builtin_amdgcn_global_load_lds(
        (const __attribute__((address_space(1))) unsigned int*)g,
        (__attribute__((address_space(3))) unsigned int*)l, 16, 0, 0);
}

template <bool HALFOUT>
__global__ __launch_bounds__(512, 2)
void gemm8p(const unsigned short* __restrict__ Am, const unsigned short* __restrict__ Bm,
            const float* __restrict__ bias, void* __restrict__ Cv,
            int M, int N, int K) {
    constexpr int BM = 256, BN = 128, BK = 64;
    constexpr int ASZ  = BM * BK;
    constexpr int BSZ  = BN * BK;
    constexpr int SLOT = ASZ + BSZ;
    extern __shared__ unsigned short smem[];

    const int tid  = threadIdx.x;
    const int lane = tid & 63;
    const int wid  = tid >> 6;
    const int wr   = wid >> 1, wc = wid & 1;
    const int q4   = lane >> 4;
    const int m16  = lane & 15;
    const int x7   = m16 & 7;

    const int nbx = N / BN;
    const int nwg = gridDim.x;
    const int q   = nwg >> 3;
    const int wg  = blockIdx.x;
    const int sz  = (wg & 7) * q + (wg >> 3);
    const int bx  = sz % nbx, by = sz / nbx;
    const int rowA0 = by * BM, rowB0 = bx * BN;

    const int rA = tid >> 3, cA = tid & 7;
    const int cg = cA ^ (rA & 7);
    const unsigned short* srcA = Am + (size_t)(rowA0 + rA) * K + cg * 8;
    const unsigned short* srcB = Bm + (size_t)(rowB0 + rA) * K + cg * 8;
    const int dA = tid * 8;

    int aoffm[4], boffn[4];
#pragma unroll
    for (int m = 0; m < 4; ++m) aoffm[m] = (wr * 64 + m * 16 + m16) * BK;
#pragma unroll
    for (int n = 0; n < 4; ++n) boffn[n] = (wc * 64 + n * 16 + m16) * BK;

    floatx4 acc[4][4];
#pragma unroll
    for (int m = 0; m < 4; ++m)
#pragma unroll
        for (int n = 0; n < 4; ++n)
#pragma unroll
            for (int r = 0; r < 4; ++r) acc[m][n][r] = 0.f;

    const int NT = K / BK;

    auto stageA = [&](int s, int t, int j) {
        gld16(srcA + (size_t)(j * 64) * K + (size_t)t * BK,
              smem + s * SLOT + j * 4096 + dA);
    };
    auto stageB = [&](int s, int t, int j) {
        gld16(srcB + (size_t)(j * 64) * K + (size_t)t * BK,
              smem + s * SLOT + ASZ + j * 4096 + dA);
    };
    auto RD = [&](const unsigned short* tA, const unsigned short* tB, int kh,
                  short8* Ra, short8* Rb) {
        const int xo = ((kh * 4 + q4) ^ x7) * 8;
#pragma unroll
        for (int m = 0; m < 4; ++m) Ra[m] = *(const short8*)(tA + aoffm[m] + xo);
#pragma unroll
        for (int n = 0; n < 4; ++n) Rb[n] = *(const short8*)(tB + boffn[n] + xo);
    };
    auto MM = [&](short8* Ra, short8* Rb) {
        __builtin_amdgcn_s_setprio(1);
#pragma unroll
        for (int m = 0; m < 4; ++m)
#pragma unroll
            for (int n = 0; n < 4; ++n)
                acc[m][n] = __builtin_amdgcn_mfma_f32_16x16x32_f16(
                    __builtin_bit_cast(half8, Ra[m]), __builtin_bit_cast(half8, Rb[n]),
                    acc[m][n], 0, 0, 0);
        __builtin_amdgcn_s_setprio(0);
    };

#pragma unroll
    for (int j = 0; j < 4; ++j) stageA(0, 0, j);
    stageB(0, 0, 0); stageB(0, 0, 1);
#pragma unroll
    for (int j = 0; j < 4; ++j) stageA(1, 1, j);
    stageB(1, 1, 0); stageB(1, 1, 1);

    asm volatile("s_waitcnt vmcnt(6)" ::: "memory");
    __builtin_amdgcn_s_barrier();
    __builtin_amdgcn_sched_barrier(0);

    short8 RA0[4], RB0[4], RA1[4], RB1[4];
    RD(smem, smem + ASZ, 0, RA0, RB0);

    int s0 = 0;
    for (int t = 0; t < NT; ++t) {
        __builtin_amdgcn_s_barrier();
        __builtin_amdgcn_sched_barrier(0);

        int s1 = s0 + 1; if (s1 == 3) s1 = 0;
        int s2 = s1 + 1; if (s2 == 3) s2 = 0;
        const unsigned short* tA  = smem + s0 * SLOT;
        const unsigned short* tB  = tA + ASZ;
        const unsigned short* tA1 = smem + s1 * SLOT;
        const unsigned short* tB1 = tA1 + ASZ;

        if (t + 2 < NT) {
#pragma unroll
            for (int j = 0; j < 4; ++j) stageA(s2, t + 2, j);
            stageB(s2, t + 2, 0); stageB(s2, t + 2, 1);
        }

        RD(tA, tB, 1, RA1, RB1);
        MM(RA0, RB0);

        if (t + 2 < NT) asm volatile("s_waitcnt vmcnt(6)" ::: "memory");
        else            asm volatile("s_waitcnt vmcnt(0)" ::: "memory");
        __builtin_amdgcn_s_barrier();
        __builtin_amdgcn_sched_barrier(0);

        if (t + 1 < NT) RD(tA1, tB1, 0, RA0, RB0);
        MM(RA1, RB1);

        s0 = s1;
    }

#pragma unroll
    for (int m = 0; m < 4; ++m) {
#pragma unroll
        for (int n = 0; n < 4; ++n) {
            int col  = rowB0 + wc * 64 + n * 16 + m16;
            float bvl = bias[col];
#pragma unroll
            for (int r = 0; r < 4; ++r) {
                int row = rowA0 + wr * 64 + m * 16 + q4 * 4 + r;
                if (HALFOUT)
                    ((unsigned short*)Cv)[(size_t)row * N + col] = f2h(acc[m][n][r] + bvl);
                else
                    ((float*)Cv)[(size_t)row * N + col] = acc[m][n][r] + bvl;
            }
        }
    }
}

// ---------------- hierarchical quaternion prefix-product scan ----------------
// r7: SEG 64->32, NSEG 32->64 — doubles scan TLP (4096 waves = 4/SIMD) and
// halves the serial per-thread qmul chain (64->32). apply's exclusive-prefix
// walk now reads partials straight from global (L2/L3-resident, 4 MB) with a
// 4-wide load batch + pairwise associative tree — one latency stall per 4
// segments instead of one per segment, and zero LDS (no occupancy cap).

struct Q { float w, x, y, z; };

__device__ __forceinline__ Q qmul(Q a, Q b) {   // a later (left), b earlier
    Q r;
    r.w = a.w * b.w - a.x * b.x - a.y * b.y - a.z * b.z;
    r.x = a.w * b.x + a.x * b.w + a.y * b.z - a.z * b.y;
    r.y = a.w * b.y - a.x * b.z + a.y * b.w + a.z * b.x;
    r.z = a.w * b.z + a.x * b.y - a.y * b.x + a.z * b.w;
    return r;
}
__device__ __forceinline__ Q qnorm(Q a) {
    float nn = a.w * a.w + a.x * a.x + a.y * a.y + a.z * a.z;
    float inv = __frsqrt_rn(nn);
    Q r; r.w = a.w * inv; r.x = a.x * inv; r.y = a.y * inv; r.z = a.z * inv;
    return r;
}
__device__ __forceinline__ Q vquat(float vx, float vy, float vz) {
    float th = sqrtf(vx * vx + vy * vy + vz * vz);
    float s_, c_;
    __sincosf(th, &s_, &c_);
    float k = __fdividef(s_, th + EPSF);
    Q q; q.w = c_; q.x = k * vx; q.y = k * vy; q.z = k * vz;
    return q;
}

#define SEG  32
#define NSEG 64

// block: 256 thr = 64 h x 4 segments; grid (NSEG/4, H/64, B)
__global__ __launch_bounds__(256)
void seg_prod_kernel(const unsigned short* __restrict__ v, float* __restrict__ partials,
                     int S, int H) {
    const int b  = blockIdx.z;
    const int h  = blockIdx.y * 64 + (threadIdx.x & 63);
    const int sg = blockIdx.x * 4 + (threadIdx.x >> 6);
    const int s0 = sg * SEG;
    const size_t vstep = (size_t)3 * H;
    const unsigned short* vp = v + ((size_t)b * S + s0) * vstep + (size_t)h * 3;

    constexpr int CH = 8;
    float ax[CH], ay[CH], az[CH], bx[CH], by[CH], bz[CH];
#pragma unroll
    for (int i = 0; i < CH; ++i) {
        ax[i] = h2f(vp[i * vstep + 0]); ay[i] = h2f(vp[i * vstep + 1]); az[i] = h2f(vp[i * vstep + 2]);
    }
    Q c = {1.f, 0.f, 0.f, 0.f};
    const int NC = SEG / CH;  // 4 chunks
    for (int cc = 0; cc < NC; cc += 2) {
        if (cc + 1 < NC) {
            const unsigned short* p = vp + (size_t)(cc + 1) * CH * vstep;
#pragma unroll
            for (int i = 0; i < CH; ++i) {
                bx[i] = h2f(p[i * vstep + 0]); by[i] = h2f(p[i * vstep + 1]); bz[i] = h2f(p[i * vstep + 2]);
            }
        }
#pragma unroll
        for (int i = 0; i < CH; ++i) c = qmul(vquat(ax[i], ay[i], az[i]), c);
        if (cc + 2 < NC) {
            const unsigned short* p = vp + (size_t)(cc + 2) * CH * vstep;
#pragma unroll
            for (int i = 0; i < CH; ++i) {
                ax[i] = h2f(p[i * vstep + 0]); ay[i] = h2f(p[i * vstep + 1]); az[i] = h2f(p[i * vstep + 2]);
            }
        }
#pragma unroll
        for (int i = 0; i < CH; ++i) c = qmul(vquat(bx[i], by[i], bz[i]), c);
    }
    float4* dst = (float4*)(partials + (((size_t)b * NSEG + sg) * H + h) * 4);
    *dst = make_float4(c.w, c.x, c.y, c.z);
}

// fused scan+apply: per-thread exclusive prefix over segment partials read
// straight from global (4-wide batches, pairwise tree), applied to re-derived
// quats; writes fp16 states; sg==NSEG-1 threads emit m_final.
__global__ __launch_bounds__(256)
void apply_kernel(const unsigned short* __restrict__ v, const float* __restrict__ partials,
                  unsigned short* __restrict__ st, float* __restrict__ m_final,
                  int S, int H) {
    const int b   = blockIdx.z;
    const int hb  = blockIdx.y * 64;
    const int hl  = threadIdx.x & 63;
    const int h   = hb + hl;
    const int sg  = blockIdx.x * 4 + (threadIdx.x >> 6);
    const int s0  = sg * SEG;
    const size_t vstep = (size_t)3 * H;
    const size_t sstep = (size_t)4 * H;
    const unsigned short* vp = v + ((size_t)b * S + s0) * vstep + (size_t)h * 3;
    unsigned short* sp = st + ((size_t)b * S + s0) * sstep + (size_t)h * 4;

    // exclusive prefix product of earlier segment partials (global reads,
    // L2/L3-resident; 4-wide independent loads + associative pairwise tree)
    const float4* pb = (const float4*)(partials) + ((size_t)b * NSEG) * H + h;
    Q R = {1.f, 0.f, 0.f, 0.f};
    int s2 = 0;
    for (; s2 + 4 <= sg; s2 += 4) {       // wave-uniform trip count
        float4 a0 = pb[(size_t)(s2 + 0) * H];
        float4 a1 = pb[(size_t)(s2 + 1) * H];
        float4 a2 = pb[(size_t)(s2 + 2) * H];
        float4 a3 = pb[(size_t)(s2 + 3) * H];
        Q q0 = {a0.x, a0.y, a0.z, a0.w};
        Q q1 = {a1.x, a1.y, a1.z, a1.w};
        Q q2 = {a2.x, a2.y, a2.z, a2.w};
        Q q3 = {a3.x, a3.y, a3.z, a3.w};
        Q t01 = qmul(q1, q0);
        Q t23 = qmul(q3, q2);
        R = qmul(qmul(t23, t01), R);
    }
    for (; s2 < sg; ++s2) {
        float4 a = pb[(size_t)s2 * H];
        Q pq = {a.x, a.y, a.z, a.w};
        R = qmul(pq, R);
    }

    constexpr int CH = 8;
    float ax[CH], ay[CH], az[CH], bx[CH], by[CH], bz[CH];
#pragma unroll
    for (int i = 0; i < CH; ++i) {
        ax[i] = h2f(vp[i * vstep + 0]); ay[i] = h2f(vp[i * vstep + 1]); az[i] = h2f(vp[i * vstep + 2]);
    }
    const int NC = SEG / CH;   // 4
    for (int cc = 0; cc < NC; cc += 2) {
        if (cc + 1 < NC) {
            const unsigned short* pp = vp + (size_t)(cc + 1) * CH * vstep;
#pragma unroll
            for (int i = 0; i < CH; ++i) {
                bx[i] = h2f(pp[i * vstep + 0]); by[i] = h2f(pp[i * vstep + 1]); bz[i] = h2f(pp[i * vstep + 2]);
            }
        }
#pragma unroll
        for (int i = 0; i < CH; ++i) {
            R = qmul(vquat(ax[i], ay[i], az[i]), R);
            Q m = qnorm(R);
            ushort4 u; u.x = f2h(m.w); u.y = f2h(m.x); u.z = f2h(m.y); u.w = f2h(m.z);
            *(ushort4*)(sp + (size_t)(cc * CH + i) * sstep) = u;
        }
        if (cc + 2 < NC) {
            const unsigned short* pp = vp + (size_t)(cc + 2) * CH * vstep;
#pragma unroll
            for (int i = 0; i < CH; ++i) {
                ax[i] = h2f(pp[i * vstep + 0]); ay[i] = h2f(pp[i * vstep + 1]); az[i] = h2f(pp[i * vstep + 2]);
            }
        }
#pragma unroll
        for (int i = 0; i < CH; ++i) {
            R = qmul(vquat(bx[i], by[i], bz[i]), R);
            Q m = qnorm(R);
            ushort4 u; u.x = f2h(m.w); u.y = f2h(m.x); u.z = f2h(m.y); u.w = f2h(m.z);
            *(ushort4*)(sp + (size_t)((cc + 1) * CH + i) * sstep) = u;
        }
    }

    if (sg == NSEG - 1) {
        Q m = qnorm(R);     // inclusive product of whole chain
        float* mf = m_final + ((size_t)b * H + h) * 4;
        mf[0] = m.w; mf[1] = m.x; mf[2] = m.y; mf[3] = m.z;
    }
}

// ---------------- launch ----------------

extern "C" void kernel_launch(void* const* d_in, const int* in_sizes, int n_in,
                              void* d_out, int out_size, void* d_ws, size_t ws_size,
                              hipStream_t stream) {
    const float* x     = (const float*)d_in[0];
    const float* W_in  = (const float*)d_in[1];
    const float* b_in  = (const float*)d_in[2];
    const float* W_out = (const float*)d_in[3];
    const float* b_out = (const float*)d_in[4];
    float* out = (float*)d_out;

    const int B = 4, S = 2048, D = 1024, H = 1024;
    const int M  = B * S;    // 8192
    const int N1 = 3 * H;    // 3072
    const int K1 = D;        // 1024
    const int N2 = D;        // 1024
    const int K2 = 4 * H;    // 4096

    // ws layout (bytes):
    //   [0, 50331648)                    v     fp16 M*N1 (48 MB)
    //   [50331648, 117440512)            st    fp16 M*K2 (64 MB); x16/wi16
    //                                    overlap here (consumed by GEMM1)
    //   [117440512, 125829120)           wo16  fp16 N2*K2 (8 MB)
    char* ws = (char*)d_ws;
    unsigned short* v    = (unsigned short*)(ws);
    unsigned short* st   = (unsigned short*)(ws + 50331648u);
    unsigned short* x16  = (unsigned short*)(ws + 50331648u);
    unsigned short* wi16 = (unsigned short*)(ws + 50331648u + 16777216u);
    unsigned short* wo16 = (unsigned short*)(ws + 117440512u);

    // partials (4 MB at NSEG=64) live in d_out — consumed by apply before
    // GEMM2 overwrites out last.
    float* partials = out;

    const int nx  = M * K1;
    const int nw  = N1 * K1;
    const int nwo = N2 * K2;
    const int n4  = (nx + nw + nwo) / 4;

    constexpr int LDSB = 147456;   // gemm8p: 3 x 48 KB
    static int attr_done = 0;
    if (!attr_done) {
        hipFuncSetAttribute(reinterpret_cast<const void*>(&gemm8p<true>),
                            hipFuncAttributeMaxDynamicSharedMemorySize, LDSB);
        hipFuncSetAttribute(reinterpret_cast<const void*>(&gemm8p<false>),
                            hipFuncAttributeMaxDynamicSharedMemorySize, LDSB);
        attr_done = 1;
    }

    prep_kernel<<<(n4 + 255) / 256, 256, 0, stream>>>(
        (const float4*)x, (ushort4*)x16, (const float4*)W_in, (ushort4*)wi16,
        (const float4*)W_out, (ushort4*)wo16, nx / 4, nw / 4, nwo / 4);

    // v = x @ W_in^T + b_in   (fp16 out; proven r5 structure)
    gemm8p<true><<<dim3((M / 256) * (N1 / 128)), 512, LDSB, stream>>>(
        x16, wi16, b_in, v, M, N1, K1);

    // hierarchical scan (NSEG=64: 4 waves/SIMD, 32-deep chains)
    dim3 sg_grid(NSEG / 4, H / 64, B);
    seg_prod_kernel<<<sg_grid, 256, 0, stream>>>(v, partials, S, H);
    apply_kernel<<<sg_grid, 256, 0, stream>>>(v, partials, st, out + (size_t)M * D, S, H);

    // out = states @ W_out^T + b_out  (fp32 out; proven r5 structure)
    gemm8p<false><<<dim3((M / 256) * (N2 / 128)), 512, LDSB, stream>>>(
        st, wo16, b_out, out, M, N2, K2);
}